// Round 2
// baseline (247.973 us; speedup 1.0000x reference)
//
#include <hip/hip_runtime.h>
#include <cstdint>
#include <cstddef>

#define P_DIM 8
#define U_DIM 256
#define V_DIM 256
#define F_DIM 12544   // 256*49

typedef __attribute__((ext_vector_type(8))) short short8;
typedef __attribute__((ext_vector_type(4))) float f32x4;

#define MFMA16(a, b, c) __builtin_amdgcn_mfma_f32_16x16x32_bf16((a), (b), (c), 0, 0, 0)

__device__ __forceinline__ unsigned short f2bf(float x) {
  unsigned u = __builtin_bit_cast(unsigned, x);
  u += 0x7FFFu + ((u >> 16) & 1u);          // RNE
  return (unsigned short)(u >> 16);
}
__device__ __forceinline__ float bf2f(unsigned short h) {
  return __builtin_bit_cast(float, ((unsigned)h) << 16);
}

// ---------------------------------------------------------------------------
// 1) vv[p*V+v] = sum_f feat_v[p][v][f]^2   (one block per row, deterministic)
// ---------------------------------------------------------------------------
__global__ __launch_bounds__(256) void vv_kernel(const float* __restrict__ fv,
                                                 float* __restrict__ vvout) {
  int row = blockIdx.x;                      // p*V + v
  const float4* src = (const float4*)(fv + (size_t)row * F_DIM);
  float s = 0.f;
  for (int i = threadIdx.x; i < F_DIM / 4; i += 256) {
    float4 x = src[i];
    s += x.x * x.x + x.y * x.y + x.z * x.z + x.w * x.w;
  }
  #pragma unroll
  for (int off = 32; off >= 1; off >>= 1) s += __shfl_xor(s, off);
  __shared__ float red[4];
  int lane = threadIdx.x & 63, wid = threadIdx.x >> 6;
  if (lane == 0) red[wid] = s;
  __syncthreads();
  if (threadIdx.x == 0) vvout[row] = red[0] + red[1] + red[2] + red[3];
}

// ---------------------------------------------------------------------------
// 2) copy feat_u -> out[0 : P*U*F]  (exact fp32 copy)
// ---------------------------------------------------------------------------
__global__ __launch_bounds__(256) void copy_kernel(const float4* __restrict__ src,
                                                   float4* __restrict__ dst, int n4) {
  for (int i = blockIdx.x * 256 + threadIdx.x; i < n4; i += gridDim.x * 256)
    dst[i] = src[i];
}

// ---------------------------------------------------------------------------
// 3) prepT: fvT[p][f][v] = bf16(feat_v[p][v][f])   (64x64 LDS tile transpose)
// grid (196, 4, 8)
// ---------------------------------------------------------------------------
__global__ __launch_bounds__(256) void prep_transpose(const float* __restrict__ fv,
                                                      unsigned short* __restrict__ fvT) {
  __shared__ unsigned short tile[64][65];
  int f0 = blockIdx.x * 64, v0 = blockIdx.y * 64, p = blockIdx.z;
  const float* src = fv + (size_t)p * V_DIM * F_DIM;
  int t = threadIdx.x;
  #pragma unroll
  for (int i = 0; i < 4; ++i) {
    int g = t + i * 256;                     // 0..1023
    int r = g >> 4;                          // v row 0..63
    int c4 = (g & 15) * 4;                   // f col
    float4 x = *(const float4*)(src + (size_t)(v0 + r) * F_DIM + f0 + c4);
    tile[r][c4 + 0] = f2bf(x.x);
    tile[r][c4 + 1] = f2bf(x.y);
    tile[r][c4 + 2] = f2bf(x.z);
    tile[r][c4 + 3] = f2bf(x.w);
  }
  __syncthreads();
  unsigned short* dst = fvT + (size_t)p * F_DIM * V_DIM;
  #pragma unroll
  for (int i = 0; i < 2; ++i) {
    int g = t + i * 256;                     // 0..511
    int f = g >> 3;                          // 0..63
    int v8 = (g & 7) * 8;
    short8 o;
    #pragma unroll
    for (int j = 0; j < 8; ++j) o[j] = (short)tile[v8 + j][f];
    *(short8*)(dst + (size_t)(f0 + f) * V_DIM + v0 + v8) = o;
  }
}

// ---------------------------------------------------------------------------
// 4) uv_gemm: partial[ks][p][u][v] = sum_{k in chunk ks} fu[u][k]*fv[v][k]
// split-bf16 (hi/lo) for fp32-grade accuracy; 128x128 tile, BK=64, 4 waves.
// LDS XOR-swizzle: byte ^= (row&7)<<4  (2-way max on ds_read_b128 -> free)
// ---------------------------------------------------------------------------
__global__ __launch_bounds__(256) void uv_gemm(const float* __restrict__ fu,
                                               const float* __restrict__ fv,
                                               float* __restrict__ part,
                                               int splitk, int chunk) {
  int bid = blockIdx.x;
  int ks = bid % splitk;
  int t4 = bid / splitk;                     // 0..31
  int nt = t4 & 1, mt = (t4 >> 1) & 1, p = t4 >> 2;
  const float* A = fu + ((size_t)p * U_DIM + mt * 128) * F_DIM;
  const float* B = fv + ((size_t)p * V_DIM + nt * 128) * F_DIM;
  int k0 = ks * chunk;

  __shared__ short AhS[128 * 64], AlS[128 * 64], BhS[128 * 64], BlS[128 * 64]; // 64 KB
  char* Ahp = (char*)AhS; char* Alp = (char*)AlS;
  char* Bhp = (char*)BhS; char* Blp = (char*)BlS;

  int tid = threadIdx.x, lane = tid & 63, wid = tid >> 6;
  int wm = wid >> 1, wn = wid & 1;           // 2x2 waves, 64x64 each

  f32x4 acc[4][4] = {};

  for (int kb = 0; kb < chunk; kb += 64) {
    int kg = k0 + kb;
    // ---- stage A and B (fp32 -> hi/lo bf16, swizzled LDS writes) ----
    #pragma unroll
    for (int i = 0; i < 4; ++i) {
      int g = tid + i * 256;                 // 0..1023
      int r = g >> 3;                        // row 0..127
      int c8 = (g & 7) * 8;                  // k offset 0..56
      int off = (r * 128 + c8 * 2) ^ ((r & 7) << 4);
      {
        const float* sa = A + (size_t)r * F_DIM + kg + c8;
        float4 x0 = *(const float4*)sa;
        float4 x1 = *(const float4*)(sa + 4);
        float xs[8] = {x0.x, x0.y, x0.z, x0.w, x1.x, x1.y, x1.z, x1.w};
        short8 h, l;
        #pragma unroll
        for (int j = 0; j < 8; ++j) {
          unsigned short hb = f2bf(xs[j]);
          h[j] = (short)hb;
          l[j] = (short)f2bf(xs[j] - bf2f(hb));
        }
        *(short8*)(Ahp + off) = h;
        *(short8*)(Alp + off) = l;
      }
      {
        const float* sb = B + (size_t)r * F_DIM + kg + c8;
        float4 x0 = *(const float4*)sb;
        float4 x1 = *(const float4*)(sb + 4);
        float xs[8] = {x0.x, x0.y, x0.z, x0.w, x1.x, x1.y, x1.z, x1.w};
        short8 h, l;
        #pragma unroll
        for (int j = 0; j < 8; ++j) {
          unsigned short hb = f2bf(xs[j]);
          h[j] = (short)hb;
          l[j] = (short)f2bf(xs[j] - bf2f(hb));
        }
        *(short8*)(Bhp + off) = h;
        *(short8*)(Blp + off) = l;
      }
    }
    __syncthreads();
    // ---- compute: 2 k-steps of 32 ----
    #pragma unroll
    for (int kk = 0; kk < 64; kk += 32) {
      int kbyte = kk * 2 + (lane >> 4) * 16;
      int rl = lane & 15;
      short8 ah[4], al[4], bh[4], bl[4];
      #pragma unroll
      for (int m = 0; m < 4; ++m) {
        int row = wm * 64 + m * 16 + rl;
        int off = (row * 128 + kbyte) ^ ((row & 7) << 4);
        ah[m] = *(const short8*)(Ahp + off);
        al[m] = *(const short8*)(Alp + off);
      }
      #pragma unroll
      for (int n = 0; n < 4; ++n) {
        int row = wn * 64 + n * 16 + rl;
        int off = (row * 128 + kbyte) ^ ((row & 7) << 4);
        bh[n] = *(const short8*)(Bhp + off);
        bl[n] = *(const short8*)(Blp + off);
      }
      #pragma unroll
      for (int m = 0; m < 4; ++m)
        #pragma unroll
        for (int n = 0; n < 4; ++n) {
          acc[m][n] = MFMA16(ah[m], bh[n], acc[m][n]);
          acc[m][n] = MFMA16(ah[m], bl[n], acc[m][n]);
          acc[m][n] = MFMA16(al[m], bh[n], acc[m][n]);
        }
    }
    __syncthreads();
  }
  // ---- store partial (C/D layout: col=lane&15, row=(lane>>4)*4+reg) ----
  float* dst = part + ((size_t)ks * P_DIM + p) * U_DIM * V_DIM;
  int rl = lane & 15, rq = lane >> 4;
  #pragma unroll
  for (int m = 0; m < 4; ++m)
    #pragma unroll
    for (int n = 0; n < 4; ++n)
      #pragma unroll
      for (int i = 0; i < 4; ++i) {
        int u = mt * 128 + wm * 64 + m * 16 + rq * 4 + i;
        int v = nt * 128 + wn * 64 + n * 16 + rl;
        dst[(size_t)u * V_DIM + v] = acc[m][n][i];
      }
}

// ---------------------------------------------------------------------------
// 5) reduce partials + softmax over v -> score (bf16).  logit = 0.1*vv - 0.2*uv
// (uu term is constant along v -> cancels in softmax)
// ---------------------------------------------------------------------------
__global__ __launch_bounds__(256) void reduce_softmax(const float* __restrict__ part,
                                                      const float* __restrict__ vv,
                                                      unsigned short* __restrict__ score,
                                                      int splitk) {
  int u = blockIdx.x & 255, p = blockIdx.x >> 8;
  int v = threadIdx.x;
  size_t base = ((size_t)p * U_DIM + u) * V_DIM + v;
  float s = 0.f;
  for (int k = 0; k < splitk; ++k)
    s += part[(size_t)k * (P_DIM * U_DIM * V_DIM) + base];
  float logit = 0.1f * vv[p * V_DIM + v] - 0.2f * s;
  float m = logit;
  #pragma unroll
  for (int off = 32; off >= 1; off >>= 1) m = fmaxf(m, __shfl_xor(m, off));
  __shared__ float red[4], red2[4];
  int lane = v & 63, wid = v >> 6;
  if (lane == 0) red[wid] = m;
  __syncthreads();
  m = fmaxf(fmaxf(red[0], red[1]), fmaxf(red[2], red[3]));
  float e = __expf(logit - m);
  float tsum = e;
  #pragma unroll
  for (int off = 32; off >= 1; off >>= 1) tsum += __shfl_xor(tsum, off);
  if (lane == 0) red2[wid] = tsum;
  __syncthreads();
  tsum = red2[0] + red2[1] + red2[2] + red2[3];
  score[base] = f2bf(e / tsum);
}

// ---------------------------------------------------------------------------
// 6) pv_gemm: neg[p][u][f] = sum_v score[p][u][v] * fvT[p][f][v]
// A (score) read direct from global (L2-resident, 1 MB); B from swizzled LDS.
// grid (98, 2, 8)
// ---------------------------------------------------------------------------
__global__ __launch_bounds__(256) void pv_gemm(const unsigned short* __restrict__ score,
                                               const unsigned short* __restrict__ fvT,
                                               float* __restrict__ outneg) {
  int ntile = blockIdx.x;                    // 0..97
  int mt = blockIdx.y;                       // 0..1
  int p = blockIdx.z;
  int n0 = ntile * 128;
  const unsigned short* Sc = score + ((size_t)p * U_DIM + mt * 128) * V_DIM;
  const unsigned short* Bt = fvT + ((size_t)p * F_DIM + n0) * V_DIM;
  __shared__ short BsS[128 * 32];            // 8 KB, slot-swizzled
  char* Bsp = (char*)BsS;
  int tid = threadIdx.x, lane = tid & 63, wid = tid >> 6;
  int wm = wid >> 1, wn = wid & 1;
  f32x4 acc[4][4] = {};

  for (int kb = 0; kb < V_DIM; kb += 32) {
    #pragma unroll
    for (int j = 0; j < 2; ++j) {
      int g = tid + j * 256;                 // 0..511
      int row = g >> 2;                      // f row 0..127
      int c = g & 3;                         // k chunk (8 bf16)
      short8 x = *(const short8*)(Bt + (size_t)row * V_DIM + kb + c * 8);
      int off = row * 64 + ((c ^ (row & 3)) * 16);
      *(short8*)(Bsp + off) = x;
    }
    __syncthreads();
    short8 a[4], b[4];
    #pragma unroll
    for (int m = 0; m < 4; ++m)
      a[m] = *(const short8*)(Sc + (size_t)(wm * 64 + m * 16 + (lane & 15)) * V_DIM
                              + kb + (lane >> 4) * 8);
    #pragma unroll
    for (int n = 0; n < 4; ++n) {
      int f = wn * 64 + n * 16 + (lane & 15);
      int off = f * 64 + ((((lane >> 4)) ^ (f & 3)) * 16);
      b[n] = *(const short8*)(Bsp + off);
    }
    #pragma unroll
    for (int m = 0; m < 4; ++m)
      #pragma unroll
      for (int n = 0; n < 4; ++n)
        acc[m][n] = MFMA16(a[m], b[n], acc[m][n]);
    __syncthreads();
  }
  int rl = lane & 15, rq = lane >> 4;
  #pragma unroll
  for (int m = 0; m < 4; ++m)
    #pragma unroll
    for (int n = 0; n < 4; ++n)
      #pragma unroll
      for (int i = 0; i < 4; ++i) {
        int u = mt * 128 + wm * 64 + m * 16 + rq * 4 + i;
        int f = n0 + wn * 64 + n * 16 + rl;
        outneg[((size_t)p * U_DIM + u) * F_DIM + f] = acc[m][n][i];
      }
}

// ---------------------------------------------------------------------------
extern "C" void kernel_launch(void* const* d_in, const int* in_sizes, int n_in,
                              void* d_out, int out_size, void* d_ws, size_t ws_size,
                              hipStream_t stream) {
  const float* fu = (const float*)d_in[0];
  const float* fv = (const float*)d_in[1];
  float* out = (float*)d_out;
  char* ws = (char*)d_ws;

  // ws layout: vv (8 KB) | score bf16 (1 MB) | fvT bf16 (51.4 MB) | partials
  float* vv = (float*)ws;
  unsigned short* score = (unsigned short*)(ws + 8192);
  unsigned short* fvT = (unsigned short*)(ws + 8192 + 1048576);
  size_t partBase = 8192 + 1048576 + (size_t)P_DIM * F_DIM * V_DIM * 2;
  float* part = (float*)(ws + partBase);

  const size_t puv4 = (size_t)P_DIM * U_DIM * V_DIM * 4;
  int splitk = 1;
  const int cands[5] = {14, 7, 4, 2, 1};
  for (int i = 0; i < 5; ++i) {
    if (partBase + (size_t)cands[i] * puv4 <= ws_size) { splitk = cands[i]; break; }
  }
  int chunk = F_DIM / splitk;                // multiple of 64 for all candidates

  vv_kernel<<<P_DIM * V_DIM, 256, 0, stream>>>(fv, vv);
  int n4 = (P_DIM * U_DIM * F_DIM) / 4;
  copy_kernel<<<2048, 256, 0, stream>>>((const float4*)fu, (float4*)out, n4);
  prep_transpose<<<dim3(F_DIM / 64, V_DIM / 64, P_DIM), 256, 0, stream>>>(fv, fvT);
  uv_gemm<<<32 * splitk, 256, 0, stream>>>(fu, fv, part, splitk, chunk);
  reduce_softmax<<<P_DIM * U_DIM, 256, 0, stream>>>(part, vv, score, splitk);
  pv_gemm<<<dim3(F_DIM / 128, U_DIM / 128, P_DIM), 256, 0, stream>>>(
      score, fvT, out + (size_t)P_DIM * U_DIM * F_DIM);
}

// Round 4
// 247.069 us; speedup vs baseline: 1.0037x; 1.0037x over previous
//
#include <hip/hip_runtime.h>
#include <cstdint>
#include <cstddef>

#define P_DIM 8
#define U_DIM 256
#define V_DIM 256
#define F_DIM 12544   // 256*49

typedef __attribute__((ext_vector_type(8))) short short8;
typedef __attribute__((ext_vector_type(4))) float f32x4;

#define MFMA16(a, b, c) __builtin_amdgcn_mfma_f32_16x16x32_bf16((a), (b), (c), 0, 0, 0)

__device__ __forceinline__ unsigned short f2bf(float x) {      // RNE (for fvT/score)
  unsigned u = __builtin_bit_cast(unsigned, x);
  u += 0x7FFFu + ((u >> 16) & 1u);
  return (unsigned short)(u >> 16);
}

// truncation split: h = top16(x), l = top16(x - h).  |x-h-l| <= ~2^-16 |x|
__device__ __forceinline__ void cvt8(float4 a, float4 b, uint4& h, uint4& l) {
  float x[8] = {a.x, a.y, a.z, a.w, b.x, b.y, b.z, b.w};
  unsigned hu[8], lu[8];
  #pragma unroll
  for (int i = 0; i < 8; ++i) {
    unsigned u = __builtin_bit_cast(unsigned, x[i]);
    unsigned ht = u & 0xFFFF0000u;
    hu[i] = ht;
    float r = x[i] - __builtin_bit_cast(float, ht);
    lu[i] = __builtin_bit_cast(unsigned, r) & 0xFFFF0000u;
  }
  h.x = (hu[0] >> 16) | hu[1]; h.y = (hu[2] >> 16) | hu[3];
  h.z = (hu[4] >> 16) | hu[5]; h.w = (hu[6] >> 16) | hu[7];
  l.x = (lu[0] >> 16) | lu[1]; l.y = (lu[2] >> 16) | lu[3];
  l.z = (lu[4] >> 16) | lu[5]; l.w = (lu[6] >> 16) | lu[7];
}

// ---------------------------------------------------------------------------
// 1) prep_fv: reads fv ONCE; writes fvT bf16 [p][f][v] + fp32 vv partials
//    grid (196, 4, 8) x 256
// ---------------------------------------------------------------------------
__global__ __launch_bounds__(256) void prep_fv(const float* __restrict__ fv,
                                               unsigned short* __restrict__ fvT,
                                               float* __restrict__ vvpart) {
  __shared__ unsigned short tile[64][65];
  __shared__ float vvp[64];
  int f0 = blockIdx.x * 64, v0 = blockIdx.y * 64, p = blockIdx.z;
  const float* src = fv + (size_t)p * V_DIM * F_DIM;
  int t = threadIdx.x;
  #pragma unroll
  for (int i = 0; i < 4; ++i) {
    int g = t + i * 256;                     // 0..1023
    int r = g >> 4;                          // v row 0..63
    int c4 = (g & 15) * 4;                   // f col
    float4 x = *(const float4*)(src + (size_t)(v0 + r) * F_DIM + f0 + c4);
    tile[r][c4 + 0] = f2bf(x.x);
    tile[r][c4 + 1] = f2bf(x.y);
    tile[r][c4 + 2] = f2bf(x.z);
    tile[r][c4 + 3] = f2bf(x.w);
    // fp32 partial sum of squares for this row (16 lanes per row)
    float ps = x.x * x.x + x.y * x.y + x.z * x.z + x.w * x.w;
    ps += __shfl_xor(ps, 1); ps += __shfl_xor(ps, 2);
    ps += __shfl_xor(ps, 4); ps += __shfl_xor(ps, 8);
    if ((t & 15) == 0) vvp[r] = ps;          // r unique per (i, 16-group)
  }
  __syncthreads();
  if (t < 64)
    vvpart[((size_t)blockIdx.x * P_DIM + p) * V_DIM + v0 + t] = vvp[t];
  unsigned short* dst = fvT + (size_t)p * F_DIM * V_DIM;
  #pragma unroll
  for (int i = 0; i < 2; ++i) {
    int g = t + i * 256;                     // 0..511
    int f = g >> 3;                          // 0..63
    int v8 = (g & 7) * 8;
    short8 o;
    #pragma unroll
    for (int j = 0; j < 8; ++j) o[j] = (short)tile[v8 + j][f];
    *(short8*)(dst + (size_t)(f0 + f) * V_DIM + v0 + v8) = o;
  }
}

// ---------------------------------------------------------------------------
// 2) vv_reduce: vv[p][v] = sum over 196 f-tiles of vvpart
// ---------------------------------------------------------------------------
__global__ __launch_bounds__(256) void vv_reduce(const float* __restrict__ vvpart,
                                                 float* __restrict__ vv) {
  int p = blockIdx.x, v = threadIdx.x;
  float s = 0.f;
  for (int j = 0; j < F_DIM / 64; ++j)
    s += vvpart[((size_t)j * P_DIM + p) * V_DIM + v];
  vv[p * V_DIM + v] = s;
}

// ---------------------------------------------------------------------------
// 3) copy feat_u -> out[0 : P*U*F]
// ---------------------------------------------------------------------------
__global__ __launch_bounds__(256) void copy_kernel(const float4* __restrict__ src,
                                                   float4* __restrict__ dst, int n4) {
  for (int i = blockIdx.x * 256 + threadIdx.x; i < n4; i += gridDim.x * 256)
    dst[i] = src[i];
}

// ---------------------------------------------------------------------------
// 4) uv_gemm: BM=256 (all u), BN=128, BK=64, split-K. 512 thr, 96 KB dyn LDS.
//    Truncation hi/lo split, 3 MFMAs per fragment pair. Reg-prefetch 2-phase.
//    LDS swizzle: byte ^= (row&7)<<4 on 128 B rows -> <=2-way (free).
// ---------------------------------------------------------------------------
__global__ __launch_bounds__(512, 1) void uv_gemm(const float* __restrict__ fu,
                                                  const float* __restrict__ fv,
                                                  float* __restrict__ part,
                                                  int splitk, int chunk) {
  extern __shared__ char smem[];
  char* Ahp = smem;                          // 256*64*2 = 32 KB
  char* Alp = smem + 32768;
  char* Bhp = smem + 65536;                  // 128*64*2 = 16 KB
  char* Blp = smem + 81920;                  // total 96 KB
  int bid = blockIdx.x;
  int ks = bid % splitk;
  int rest = bid / splitk;
  int nt = rest & 1, p = rest >> 1;
  const float* A = fu + (size_t)p * U_DIM * F_DIM;
  const float* B = fv + ((size_t)p * V_DIM + nt * 128) * F_DIM;
  int k0 = ks * chunk;
  int nkt = chunk >> 6;
  int tid = threadIdx.x, lane = tid & 63, wid = tid >> 6;
  int wm = wid >> 2, wn = wid & 3;           // 2M x 4N waves; wave tile 128x32
  int rl = lane & 15;
  f32x4 acc[8][2] = {};
  float4 ra[8];                              // staged A: 4 chunks x 8 floats
  float4 rb[4];                              // staged B: 2 chunks x 8 floats

#define LOAD_TILE(kg)                                                          \
  do {                                                                         \
    _Pragma("unroll") for (int j = 0; j < 4; ++j) {                            \
      int g = tid + j * 512; int r = g >> 3; int c8 = (g & 7) * 8;             \
      const float* s = A + (size_t)r * F_DIM + (kg) + c8;                      \
      ra[2 * j] = *(const float4*)s; ra[2 * j + 1] = *(const float4*)(s + 4);  \
    }                                                                          \
    _Pragma("unroll") for (int j = 0; j < 2; ++j) {                            \
      int g = tid + j * 512; int r = g >> 3; int c8 = (g & 7) * 8;             \
      const float* s = B + (size_t)r * F_DIM + (kg) + c8;                      \
      rb[2 * j] = *(const float4*)s; rb[2 * j + 1] = *(const float4*)(s + 4);  \
    }                                                                          \
  } while (0)

  LOAD_TILE(k0);
  for (int kt = 0; kt < nkt; ++kt) {
    // convert staged regs -> swizzled LDS (hi/lo planes)
    #pragma unroll
    for (int j = 0; j < 4; ++j) {
      int g = tid + j * 512;
      int r = g >> 3;
      int off = (r * 128 + (g & 7) * 16) ^ ((r & 7) << 4);
      uint4 h, l;
      cvt8(ra[2 * j], ra[2 * j + 1], h, l);
      *(uint4*)(Ahp + off) = h;
      *(uint4*)(Alp + off) = l;
    }
    #pragma unroll
    for (int j = 0; j < 2; ++j) {
      int g = tid + j * 512;
      int r = g >> 3;
      int off = (r * 128 + (g & 7) * 16) ^ ((r & 7) << 4);
      uint4 h, l;
      cvt8(rb[2 * j], rb[2 * j + 1], h, l);
      *(uint4*)(Bhp + off) = h;
      *(uint4*)(Blp + off) = l;
    }
    __syncthreads();
    if (kt + 1 < nkt) LOAD_TILE(k0 + (kt + 1) * 64);   // prefetch under compute
    #pragma unroll
    for (int kk = 0; kk < 2; ++kk) {
      int kbyte = kk * 64 + (lane >> 4) * 16;
      short8 bh[2], bl[2];
      #pragma unroll
      for (int n = 0; n < 2; ++n) {
        int row = wn * 32 + n * 16 + rl;
        int off = (row * 128 + kbyte) ^ ((row & 7) << 4);
        bh[n] = *(const short8*)(Bhp + off);
        bl[n] = *(const short8*)(Blp + off);
      }
      short8 ah[8], al[8];
      #pragma unroll
      for (int m = 0; m < 8; ++m) {
        int row = wm * 128 + m * 16 + rl;
        int off = (row * 128 + kbyte) ^ ((row & 7) << 4);
        ah[m] = *(const short8*)(Ahp + off);
        al[m] = *(const short8*)(Alp + off);
      }
      #pragma unroll
      for (int m = 0; m < 8; ++m)
        #pragma unroll
        for (int n = 0; n < 2; ++n) {
          acc[m][n] = MFMA16(ah[m], bh[n], acc[m][n]);
          acc[m][n] = MFMA16(ah[m], bl[n], acc[m][n]);
          acc[m][n] = MFMA16(al[m], bh[n], acc[m][n]);
        }
    }
    __syncthreads();
  }
#undef LOAD_TILE
  // store partial (C/D: col=lane&15, row=(lane>>4)*4+i)
  float* dst = part + ((size_t)ks * P_DIM + p) * U_DIM * V_DIM;
  int rq = lane >> 4;
  #pragma unroll
  for (int m = 0; m < 8; ++m)
    #pragma unroll
    for (int n = 0; n < 2; ++n)
      #pragma unroll
      for (int i = 0; i < 4; ++i) {
        int u = wm * 128 + m * 16 + rq * 4 + i;
        int v = nt * 128 + wn * 32 + n * 16 + rl;
        dst[(size_t)u * V_DIM + v] = acc[m][n][i];
      }
}

// ---------------------------------------------------------------------------
// 5) reduce partials + softmax over v -> bf16 score.  logit = 0.1*vv - 0.2*uv
// ---------------------------------------------------------------------------
__global__ __launch_bounds__(256) void reduce_softmax(const float* __restrict__ part,
                                                      const float* __restrict__ vv,
                                                      unsigned short* __restrict__ score,
                                                      int splitk) {
  int u = blockIdx.x & 255, p = blockIdx.x >> 8;
  int v = threadIdx.x;
  size_t base = ((size_t)p * U_DIM + u) * V_DIM + v;
  float s = 0.f;
  for (int k = 0; k < splitk; ++k)
    s += part[(size_t)k * (P_DIM * U_DIM * V_DIM) + base];
  float logit = 0.1f * vv[p * V_DIM + v] - 0.2f * s;
  float m = logit;
  #pragma unroll
  for (int off = 32; off >= 1; off >>= 1) m = fmaxf(m, __shfl_xor(m, off));
  __shared__ float red[4], red2[4];
  int lane = v & 63, wid = v >> 6;
  if (lane == 0) red[wid] = m;
  __syncthreads();
  m = fmaxf(fmaxf(red[0], red[1]), fmaxf(red[2], red[3]));
  float e = __expf(logit - m);
  float tsum = e;
  #pragma unroll
  for (int off = 32; off >= 1; off >>= 1) tsum += __shfl_xor(tsum, off);
  if (lane == 0) red2[wid] = tsum;
  __syncthreads();
  tsum = red2[0] + red2[1] + red2[2] + red2[3];
  score[base] = f2bf(e / tsum);
}

// ---------------------------------------------------------------------------
// 6) pv_gemm: BM=256 (all u, fvT read once), BN=128 f, BK=32 over V. 512 thr.
//    A (score) direct from global (L2-resident); B via 8 KB swizzled LDS.
//    grid (98, 8)
// ---------------------------------------------------------------------------
__global__ __launch_bounds__(512) void pv_gemm(const unsigned short* __restrict__ score,
                                               const unsigned short* __restrict__ fvT,
                                               float* __restrict__ outneg) {
  int bx = blockIdx.x;                       // f tile 0..97
  int p = blockIdx.y;
  int n0 = bx * 128;
  const unsigned short* Sc = score + (size_t)p * U_DIM * V_DIM;
  const unsigned short* Bt = fvT + ((size_t)p * F_DIM + n0) * V_DIM;
  __shared__ short BsS[128 * 32];            // 8 KB
  char* Bsp = (char*)BsS;
  int tid = threadIdx.x, lane = tid & 63, wid = tid >> 6;
  int wm = wid >> 2, wn = wid & 3;           // wave tile 128x32
  int rl = lane & 15, rq = lane >> 4;
  f32x4 acc[8][2] = {};

  for (int kb = 0; kb < V_DIM; kb += 32) {
    {                                        // stage B: 512 chunks, 1/thread
      int row = tid >> 2;                    // f row 0..127
      int c = tid & 3;                       // 8-short chunk
      short8 x = *(const short8*)(Bt + (size_t)row * V_DIM + kb + c * 8);
      int off = row * 64 + ((c ^ ((row >> 1) & 3)) * 16);
      *(short8*)(Bsp + off) = x;
    }
    __syncthreads();
    short8 a[8], b[2];
    #pragma unroll
    for (int m = 0; m < 8; ++m)
      a[m] = *(const short8*)(Sc + (size_t)(wm * 128 + m * 16 + rl) * V_DIM
                              + kb + rq * 8);
    #pragma unroll
    for (int n = 0; n < 2; ++n) {
      int f = wn * 32 + n * 16 + rl;
      int off = f * 64 + ((rq ^ ((f >> 1) & 3)) * 16);
      b[n] = *(const short8*)(Bsp + off);
    }
    #pragma unroll
    for (int m = 0; m < 8; ++m)
      #pragma unroll
      for (int n = 0; n < 2; ++n)
        acc[m][n] = MFMA16(a[m], b[n], acc[m][n]);
    __syncthreads();
  }
  #pragma unroll
  for (int m = 0; m < 8; ++m)
    #pragma unroll
    for (int n = 0; n < 2; ++n)
      #pragma unroll
      for (int i = 0; i < 4; ++i) {
        int u = wm * 128 + m * 16 + rq * 4 + i;
        int f = n0 + wn * 32 + n * 16 + rl;
        outneg[((size_t)p * U_DIM + u) * F_DIM + f] = acc[m][n][i];
      }
}

// ---------------------------------------------------------------------------
extern "C" void kernel_launch(void* const* d_in, const int* in_sizes, int n_in,
                              void* d_out, int out_size, void* d_ws, size_t ws_size,
                              hipStream_t stream) {
  const float* fu = (const float*)d_in[0];
  const float* fv = (const float*)d_in[1];
  float* out = (float*)d_out;
  char* ws = (char*)d_ws;

  // ws: vv 8KB | score 1MB | fvT 51.4MB | vvpart 1.6MB | part (splitk*2MB)
  float* vv = (float*)ws;
  unsigned short* score = (unsigned short*)(ws + 8192);
  unsigned short* fvT = (unsigned short*)(ws + 8192 + 1048576);
  size_t vvpartBase = 8192 + 1048576 + (size_t)P_DIM * F_DIM * V_DIM * 2;
  float* vvpart = (float*)(ws + vvpartBase);
  size_t partBase = vvpartBase + (size_t)(F_DIM / 64) * P_DIM * V_DIM * 4;
  float* part = (float*)(ws + partBase);

  const size_t puv4 = (size_t)P_DIM * U_DIM * V_DIM * 4;
  int splitk = 1;
  const int cands[5] = {14, 7, 4, 2, 1};
  for (int i = 0; i < 5; ++i) {
    if (partBase + (size_t)cands[i] * puv4 <= ws_size) { splitk = cands[i]; break; }
  }
  int chunk = F_DIM / splitk;                // multiple of 64 for all candidates

  prep_fv<<<dim3(F_DIM / 64, V_DIM / 64, P_DIM), 256, 0, stream>>>(fv, fvT, vvpart);
  vv_reduce<<<P_DIM, 256, 0, stream>>>(vvpart, vv);
  int n4 = (P_DIM * U_DIM * F_DIM) / 4;
  copy_kernel<<<2048, 256, 0, stream>>>((const float4*)fu, (float4*)out, n4);
  uv_gemm<<<splitk * 2 * P_DIM, 512, 98304, stream>>>(fu, fv, part, splitk, chunk);
  reduce_softmax<<<P_DIM * U_DIM, 256, 0, stream>>>(part, vv, score, splitk);
  pv_gemm<<<dim3(F_DIM / 128, P_DIM), 512, 0, stream>>>(
      score, fvT, out + (size_t)P_DIM * U_DIM * F_DIM);
}